// Round 3
// baseline (2331.717 us; speedup 1.0000x reference)
//
#include <hip/hip_runtime.h>

// VQ-VAE forward loss on MI355X (gfx950).
// loss = 2.25/(N*D) * [ sum(x^2) + sum_n min_k(||e_k||^2 - 2 x_n.e_k) ]
// R3: producer/consumer pipeline. 1 producer wave DMAs fp32 X tiles into
// double-buffered LDS via global_load_lds (its vmcnt(0)-at-barrier is the
// "tile ready" handshake; consumer vmcnt counters are independent -> compute
// overlaps DMA). fp8-e4m3 MFMA halves B-side L2 traffic. XOR bank swizzle
// baked into DMA source addresses.

#define NROWS   262144
#define DDIM    480
#define KCODES  512
#define BM      32                         // rows per tile
#define TILE_BYTES (BM * DDIM * 4)         // 61440
#define TPB     32                         // tiles per block
#define NBLK    (NROWS / BM / TPB)         // 256
#define NT      576                        // 8 consumer waves + 1 producer
#define CHUNKS  (TILE_BYTES / 1024)        // 60 DMA instructions per tile
#define LDS_RED (2 * TILE_BYTES)           // red[2][32][4] floats
#define LDS_RDW (LDS_RED + 1024)           // redw[9]
#define LDS_TOT (LDS_RDW + 64)

typedef float f32x4 __attribute__((ext_vector_type(4)));

__device__ __forceinline__ float fp8dec(int b) {
    return __builtin_amdgcn_cvt_f32_fp8(b & 0xff, 0);
}

// Codebook -> fp8 e4m3 in ws; ||e_k||^2 from the DECODED fp8 values (self-
// consistent quantized geometry); zero d_out.
__global__ void vq_setup(const float* __restrict__ e, unsigned char* __restrict__ e8,
                         float* __restrict__ esq, float* __restrict__ out) {
    const int k = blockIdx.x;   // one code row per block (1 wave)
    const int t = threadIdx.x;
    if (k == 0 && t == 0) out[0] = 0.0f;
    float s = 0.0f;
    for (int d = t; d < DDIM; d += 64) {
        float v = e[k * DDIM + d];
        int enc = __builtin_amdgcn_cvt_pk_fp8_f32(v, 0.0f, 0, false) & 0xff;
        e8[k * DDIM + d] = (unsigned char)enc;
        float fd = fp8dec(enc);
        s += fd * fd;
    }
    #pragma unroll
    for (int m = 32; m >= 1; m >>= 1) s += __shfl_xor(s, m, 64);
    if (t == 0) esq[k] = s;
}

__global__ __launch_bounds__(NT, 3) void vq_main(const float* __restrict__ x,
        const unsigned char* __restrict__ e8, const float* __restrict__ esq,
        float* __restrict__ out) {
    extern __shared__ __align__(16) char smem[];
    float (*red)[BM][4] = (float (*)[BM][4])(smem + LDS_RED);
    float* redw = (float*)(smem + LDS_RDW);

    const int tid  = threadIdx.x;
    const int wave = tid >> 6;
    const int lane = tid & 63;
    const int lrow = lane & 15;
    const int quad = lane >> 4;
    const long tile0 = (long)blockIdx.x * TPB;

    // consumer role params (producer lanes get clamped-but-valid indices)
    const int cw   = (wave < 8) ? wave : 0;
    const int r    = cw & 1;              // rowtile within the 32-row tile
    const int ch   = cw >> 1;             // 128-code slice
    const int rowb = r * 16;

    float esv[8];
    #pragma unroll
    for (int ct = 0; ct < 8; ++ct)
        esv[ct] = esq[ch * 128 + ct * 16 + lrow];
    const unsigned char* bbase = e8 + (size_t)(ch * 128 + lrow) * DDIM + quad * 8;

    float xsq = 0.0f, runSum = 0.0f;

    // ---- producer: prologue DMA of tile 0 ----
    if (wave == 8) {
        const char* xt = (const char*)x + tile0 * TILE_BYTES;
        int row = 0, cl = lane;
        #pragma unroll 4
        for (int i = 0; i < CHUNKS; ++i) {
            int gc = row * 120 + (cl ^ (row & 7));
            __builtin_amdgcn_global_load_lds(
                (const __attribute__((address_space(1))) void*)(xt + gc * 16),
                (__attribute__((address_space(3))) void*)(smem + i * 1024 + lane * 16),
                16, 0, 0);
            cl += 64; if (cl >= 120) { cl -= 120; ++row; }
        }
    }

    for (int t = 0; t < TPB; ++t) {
        __syncthreads();   // producer drains vmcnt(0) here => buf[t&1] is full

        if (wave == 8) {
            if (t + 1 < TPB) {
                const char* xt = (const char*)x + (tile0 + t + 1) * TILE_BYTES;
                char* lb = smem + ((t + 1) & 1) * TILE_BYTES;
                int row = 0, cl = lane;
                #pragma unroll 4
                for (int i = 0; i < CHUNKS; ++i) {
                    int gc = row * 120 + (cl ^ (row & 7));
                    __builtin_amdgcn_global_load_lds(
                        (const __attribute__((address_space(1))) void*)(xt + gc * 16),
                        (__attribute__((address_space(3))) void*)(lb + i * 1024 + lane * 16),
                        16, 0, 0);
                    cl += 64; if (cl >= 120) { cl -= 120; ++row; }
                }
            }
        } else {
            // fold previous tile's cross-wave row mins (overlaps DMA)
            if (t > 0 && tid < 32) {
                const float* rr = red[(t - 1) & 1][tid];
                runSum += fminf(fminf(rr[0], rr[1]), fminf(rr[2], rr[3]));
            }

            const f32x4* A4 = (const f32x4*)(smem + (t & 1) * TILE_BYTES);
            const int row  = rowb + lrow;
            const int rw   = row & 7;
            const int arow = row * 120;

            f32x4 acc[8];
            #pragma unroll
            for (int ct = 0; ct < 8; ++ct) acc[ct] = (f32x4){0.f, 0.f, 0.f, 0.f};

            long Bb[2][8];
            #pragma unroll
            for (int ct = 0; ct < 8; ++ct)
                Bb[0][ct] = *(const long*)(bbase + (size_t)ct * 16 * DDIM);

            #pragma unroll
            for (int dk = 0; dk < 15; ++dk) {   // D = 15*32
                const int cur = dk & 1;
                if (dk < 14) {
                    #pragma unroll
                    for (int ct = 0; ct < 8; ++ct)
                        Bb[cur ^ 1][ct] = *(const long*)(bbase + (size_t)ct * 16 * DDIM + (dk + 1) * 32);
                }
                f32x4 a0 = A4[arow + dk * 8 + ((quad * 2 + 0) ^ rw)];
                f32x4 a1 = A4[arow + dk * 8 + ((quad * 2 + 1) ^ rw)];
                xsq += a0[0]*a0[0] + a0[1]*a0[1] + a0[2]*a0[2] + a0[3]*a0[3]
                     + a1[0]*a1[0] + a1[1]*a1[1] + a1[2]*a1[2] + a1[3]*a1[3];
                int w0 = 0, w1 = 0;
                w0 = __builtin_amdgcn_cvt_pk_fp8_f32(a0[0], a0[1], w0, false);
                w0 = __builtin_amdgcn_cvt_pk_fp8_f32(a0[2], a0[3], w0, true);
                w1 = __builtin_amdgcn_cvt_pk_fp8_f32(a1[0], a1[1], w1, false);
                w1 = __builtin_amdgcn_cvt_pk_fp8_f32(a1[2], a1[3], w1, true);
                long Af = ((long)(unsigned)w1 << 32) | (unsigned)w0;
                #pragma unroll
                for (int ct = 0; ct < 8; ++ct)
                    acc[ct] = __builtin_amdgcn_mfma_f32_16x16x32_fp8_fp8(Af, Bb[cur][ct], acc[ct], 0, 0, 0);
            }

            // min over this wave's 128 codes; acc[ct][j] = (row16=quad*4+j, code=ct*16+lrow)
            float rmin[4] = {1e30f, 1e30f, 1e30f, 1e30f};
            #pragma unroll
            for (int ct = 0; ct < 8; ++ct)
                #pragma unroll
                for (int j = 0; j < 4; ++j)
                    rmin[j] = fminf(rmin[j], esv[ct] - 2.0f * acc[ct][j]);
            #pragma unroll
            for (int j = 0; j < 4; ++j) {
                float v = rmin[j];
                v = fminf(v, __shfl_xor(v, 1, 64));
                v = fminf(v, __shfl_xor(v, 2, 64));
                v = fminf(v, __shfl_xor(v, 4, 64));
                v = fminf(v, __shfl_xor(v, 8, 64));
                if (lrow == 0) red[t & 1][rowb + quad * 4 + j][ch] = v;
            }
        }
    }

    __syncthreads();
    // each element of each tile was read by exactly 4 waves (ch=0..3) -> /4
    float contrib = 0.25f * xsq;
    if (tid < 32) {
        const float* rr = red[(TPB - 1) & 1][tid];
        runSum += fminf(fminf(rr[0], rr[1]), fminf(rr[2], rr[3]));
        contrib += runSum;
    }
    #pragma unroll
    for (int m = 32; m >= 1; m >>= 1) contrib += __shfl_xor(contrib, m, 64);
    if (lane == 0) redw[wave] = contrib;
    __syncthreads();
    if (tid == 0) {
        const float SCALE = 2.25f / ((float)NROWS * (float)DDIM);
        float s = 0.f;
        #pragma unroll
        for (int w = 0; w < 9; ++w) s += redw[w];
        atomicAdd(out, s * SCALE);
    }
}

extern "C" void kernel_launch(void* const* d_in, const int* in_sizes, int n_in,
                              void* d_out, int out_size, void* d_ws, size_t ws_size,
                              hipStream_t stream) {
    (void)in_sizes; (void)n_in; (void)out_size; (void)ws_size;
    const float* x = (const float*)d_in[0];   // [262144, 480] fp32
    const float* e = (const float*)d_in[1];   // [512, 480] fp32
    float* out = (float*)d_out;               // scalar fp32
    unsigned char* e8 = (unsigned char*)d_ws;                   // 512*480 = 245760 B
    float* esq = (float*)((char*)d_ws + KCODES * DDIM);         // 512*4 B

    (void)hipFuncSetAttribute((const void*)vq_main,
        hipFuncAttributeMaxDynamicSharedMemorySize, LDS_TOT);

    vq_setup<<<KCODES, 64, 0, stream>>>(e, e8, esq, out);
    vq_main<<<NBLK, NT, LDS_TOT, stream>>>(x, e8, esq, out);
}